// Round 10
// baseline (628.808 us; speedup 1.0000x reference)
//
#include <hip/hip_runtime.h>
#include <math.h>

#define N_NODES 100000
#define N_EDGES 6400000
#define DIM     128
#define NROLES  8
#define ALPHA   0.15f
#define PR_ITERS 10

// dst buckets: 256 nodes each (iteration blocks); src buckets: 512 (degree)
#define DSH      8
#define DBS      256
#define NDB      391              // ceil(100000/256)
#define SSH      9
#define SBS      512
#define NSB      196              // ceil(100000/512)
#define NBT      587              // NDB + NSB
#define NBLK_BIN 256
#define CHUNK    25000            // E / NBLK_BIN exactly
#define NBIN     391              // src bins of 256 nodes (u16 re-encoding)
#define CAP16    24576            // padded u16 records per bucket (max ~17K)

// ---------------------------------------------------------------------------
// K0: tiny fp64 solve on device: M = A^T (A A^T)^{-1}, A = H^T (4 x R).
// ---------------------------------------------------------------------------
__global__ void k_prep_M(const float* __restrict__ H, float* __restrict__ Mout) {
    if (threadIdx.x != 0 || blockIdx.x != 0) return;
    double G[4][4];
    for (int i = 0; i < 4; ++i)
        for (int j = 0; j < 4; ++j) {
            double s = 0.0;
            for (int r = 0; r < NROLES; ++r)
                s += (double)H[r * 4 + i] * (double)H[r * 4 + j];
            G[i][j] = s;
        }
    double aug[4][8];
    for (int i = 0; i < 4; ++i)
        for (int j = 0; j < 4; ++j) {
            aug[i][j] = G[i][j];
            aug[i][j + 4] = (i == j) ? 1.0 : 0.0;
        }
    for (int c = 0; c < 4; ++c) {
        int p = c; double best = fabs(aug[c][c]);
        for (int r = c + 1; r < 4; ++r) {
            double v = fabs(aug[r][c]);
            if (v > best) { best = v; p = r; }
        }
        if (p != c)
            for (int j = 0; j < 8; ++j) {
                double t = aug[c][j]; aug[c][j] = aug[p][j]; aug[p][j] = t;
            }
        double piv = aug[c][c];
        for (int j = 0; j < 8; ++j) aug[c][j] /= piv;
        for (int r = 0; r < 4; ++r) {
            if (r == c) continue;
            double f = aug[r][c];
            for (int j = 0; j < 8; ++j) aug[r][j] -= f * aug[c][j];
        }
    }
    for (int r = 0; r < NROLES; ++r)
        for (int k = 0; k < 4; ++k) {
            double s = 0.0;
            for (int j = 0; j < 4; ++j)
                s += (double)H[r * 4 + j] * aug[j][k + 4];
            Mout[r * 4 + k] = (float)s;
        }
}

// ---------------------------------------------------------------------------
// K1: per-block LDS histograms: dst-buckets [0,391) + src-buckets [391,587).
// ---------------------------------------------------------------------------
__global__ __launch_bounds__(256)
void k_hist(const int* __restrict__ src, const int* __restrict__ dst,
            unsigned* __restrict__ counts) {
    __shared__ unsigned h[NBT];
    for (int i = threadIdx.x; i < NBT; i += 256) h[i] = 0;
    __syncthreads();
    int beg = blockIdx.x * CHUNK;
    int t = threadIdx.x;
    int mainEnd = beg + 24576;
    for (int e = beg + t * 4; e < mainEnd; e += 1024) {
        int4 s4 = *(const int4*)(src + e);
        int4 d4 = *(const int4*)(dst + e);
        atomicAdd(&h[((unsigned)d4.x) >> DSH], 1u);
        atomicAdd(&h[((unsigned)d4.y) >> DSH], 1u);
        atomicAdd(&h[((unsigned)d4.z) >> DSH], 1u);
        atomicAdd(&h[((unsigned)d4.w) >> DSH], 1u);
        atomicAdd(&h[NDB + (((unsigned)s4.x) >> SSH)], 1u);
        atomicAdd(&h[NDB + (((unsigned)s4.y) >> SSH)], 1u);
        atomicAdd(&h[NDB + (((unsigned)s4.z) >> SSH)], 1u);
        atomicAdd(&h[NDB + (((unsigned)s4.w) >> SSH)], 1u);
    }
    for (int e = mainEnd + t; e < beg + CHUNK; e += 256) {
        atomicAdd(&h[((unsigned)dst[e]) >> DSH], 1u);
        atomicAdd(&h[NDB + (((unsigned)src[e]) >> SSH)], 1u);
    }
    __syncthreads();
    for (int i = threadIdx.x; i < NBT; i += 256)
        counts[blockIdx.x * NBT + i] = h[i];
}

// ---------------------------------------------------------------------------
// K2a: per-bucket exclusive scan over the 256 per-block counts.
// ---------------------------------------------------------------------------
__global__ __launch_bounds__(256)
void k_scanA(const unsigned* __restrict__ counts, unsigned* __restrict__ offs,
             unsigned* __restrict__ btot) {
    int bucket = blockIdx.x, t = threadIdx.x, lane = t & 63, wv = t >> 6;
    unsigned v = counts[t * NBT + bucket], x = v;
    #pragma unroll
    for (int o = 1; o < 64; o <<= 1) {
        unsigned y = __shfl_up(x, o);
        if (lane >= o) x += y;
    }
    __shared__ unsigned wsum[4];
    if (lane == 63) wsum[wv] = x;
    __syncthreads();
    unsigned carry = 0;
    for (int w = 0; w < wv; ++w) carry += wsum[w];
    x += carry;
    offs[t * NBT + bucket] = x - v;       // exclusive
    if (t == 255) btot[bucket] = x;       // inclusive total
}

// ---------------------------------------------------------------------------
// K2b: exclusive scan of bucket totals. half 0: 391 dst -> bases[0..391];
// half 1: 196 src -> bases[512..708]. 512 threads.
// ---------------------------------------------------------------------------
__global__ __launch_bounds__(512)
void k_scanB(const unsigned* __restrict__ btot, unsigned* __restrict__ bases) {
    int half = blockIdx.x;
    int len  = half ? NSB : NDB;
    int t = threadIdx.x, lane = t & 63, wv = t >> 6;
    unsigned v = (t < len) ? btot[(half ? NDB : 0) + t] : 0u, x = v;
    #pragma unroll
    for (int o = 1; o < 64; o <<= 1) {
        unsigned y = __shfl_up(x, o);
        if (lane >= o) x += y;
    }
    __shared__ unsigned wsum[8];
    if (lane == 63) wsum[wv] = x;
    __syncthreads();
    unsigned carry = 0;
    for (int w = 0; w < wv; ++w) carry += wsum[w];
    x += carry;
    if (t <= len) bases[half * 512 + t] = x - v;   // exclusive
}

// ---------------------------------------------------------------------------
// K3: placement — two record streams:
//   rec  (u32, grouped by 256-node dst-bucket): (dst_local(8) << 17) | src(17)
//   recs (u16, grouped by 512-node src-bucket): src_local (degree count)
// ---------------------------------------------------------------------------
__global__ __launch_bounds__(256)
void k_place(const int* __restrict__ src, const int* __restrict__ dst,
             const unsigned* __restrict__ offs, const unsigned* __restrict__ bases,
             unsigned* __restrict__ rec, unsigned short* __restrict__ recs) {
    __shared__ unsigned cD[NDB];
    __shared__ unsigned cS[NSB];
    for (int i = threadIdx.x; i < NDB; i += 256)
        cD[i] = bases[i] + offs[blockIdx.x * NBT + i];
    for (int i = threadIdx.x; i < NSB; i += 256)
        cS[i] = bases[512 + i] + offs[blockIdx.x * NBT + NDB + i];
    __syncthreads();
    int beg = blockIdx.x * CHUNK;
    int t = threadIdx.x;
    int mainEnd = beg + 24576;
    for (int e = beg + t * 4; e < mainEnd; e += 1024) {
        int4 s4 = *(const int4*)(src + e);
        int4 d4 = *(const int4*)(dst + e);
        #pragma unroll
        for (int k = 0; k < 4; ++k) {
            unsigned s = (unsigned)((&s4.x)[k]);
            unsigned d = (unsigned)((&d4.x)[k]);
            unsigned pos = atomicAdd(&cD[d >> DSH], 1u);
            rec[pos] = ((d & (DBS - 1)) << 17) | s;
            unsigned pos2 = atomicAdd(&cS[s >> SSH], 1u);
            recs[pos2] = (unsigned short)(s & (SBS - 1));
        }
    }
    for (int e = mainEnd + t; e < beg + CHUNK; e += 256) {
        unsigned s = (unsigned)src[e];
        unsigned d = (unsigned)dst[e];
        unsigned pos = atomicAdd(&cD[d >> DSH], 1u);
        rec[pos] = ((d & (DBS - 1)) << 17) | s;
        unsigned pos2 = atomicAdd(&cS[s >> SSH], 1u);
        recs[pos2] = (unsigned short)(s & (SBS - 1));
    }
}

// ---------------------------------------------------------------------------
// K4: per-src-bucket degree count (LDS u32) + fused init of s and val0.
// ---------------------------------------------------------------------------
__global__ __launch_bounds__(256)
void k_count_init(const unsigned short* __restrict__ recs,
                  const unsigned* __restrict__ bases,
                  float* __restrict__ deg, float* __restrict__ s,
                  float* __restrict__ val0) {
    __shared__ unsigned cnt[SBS];
    int t = threadIdx.x;
    cnt[t] = 0; cnt[t + 256] = 0;
    __syncthreads();
    int b = blockIdx.x;
    unsigned st = bases[512 + b], en = bases[512 + b + 1];
    unsigned a = (st + 7u) & ~7u;
    if (a > en) a = en;
    for (unsigned i = st + t; i < a; i += 256)
        atomicAdd(&cnt[recs[i]], 1u);
    unsigned mainN = (en - a) & ~2047u;
    const uint4* rp = (const uint4*)(recs + a);
    for (unsigned i = t; i * 8u < mainN; i += 256) {
        uint4 r = rp[i];
        atomicAdd(&cnt[r.x & 0xFFFFu], 1u); atomicAdd(&cnt[r.x >> 16], 1u);
        atomicAdd(&cnt[r.y & 0xFFFFu], 1u); atomicAdd(&cnt[r.y >> 16], 1u);
        atomicAdd(&cnt[r.z & 0xFFFFu], 1u); atomicAdd(&cnt[r.z >> 16], 1u);
        atomicAdd(&cnt[r.w & 0xFFFFu], 1u); atomicAdd(&cnt[r.w >> 16], 1u);
    }
    for (unsigned i = a + mainN + t; i < en; i += 256)
        atomicAdd(&cnt[recs[i]], 1u);
    __syncthreads();
    #pragma unroll
    for (int k = 0; k < 2; ++k) {
        int v = b * SBS + t + k * 256;
        if (v < N_NODES) {
            float d = (float)cnt[t + k * 256];
            float sv = (1.0f - ALPHA) / fmaxf(d, 1.0f);
            deg[v] = d;
            s[v] = sv;
            val0[v] = sv * (1.0f / (float)N_NODES);
        }
    }
}

// ---------------------------------------------------------------------------
// K4b: LDS-resident re-encode: per dst-bucket, counting-sort records by
// src-bin (256 nodes) into u16 = (dst_local<<8)|src_local8, written
// COALESCED to padded rec16[b*CAP16]; 392-entry offset table per bucket.
// ---------------------------------------------------------------------------
__global__ __launch_bounds__(256)
void k_sort2(const unsigned* __restrict__ rec, const unsigned* __restrict__ bases,
             unsigned short* __restrict__ rec16, unsigned* __restrict__ tabG) {
    __shared__ unsigned cur[NBIN];          // hist, then cursors
    __shared__ unsigned tabL[NBIN + 1];     // exclusive offsets (relative)
    __shared__ unsigned wsum2[4];
    __shared__ unsigned short buf[CAP16];
    int t = threadIdx.x, lane = t & 63, wv = t >> 6;
    int b = blockIdx.x;
    unsigned st = bases[b], en = bases[b + 1];
    for (int i = t; i < NBIN; i += 256) cur[i] = 0;
    __syncthreads();
    // pass 1: histogram of src>>8
    for (unsigned i = st + t; i < en; i += 256)
        atomicAdd(&cur[(rec[i] & 0x1FFFFu) >> 8], 1u);
    __syncthreads();
    // block exclusive scan (2 bins per thread)
    unsigned loc0 = 0, loc1 = 0, sum = 0;
    if (2 * t < NBIN)     loc0 = cur[2 * t];
    if (2 * t + 1 < NBIN) loc1 = cur[2 * t + 1];
    sum = loc0 + loc1;
    unsigned x = sum;
    #pragma unroll
    for (int o = 1; o < 64; o <<= 1) {
        unsigned y = __shfl_up(x, o);
        if (lane >= o) x += y;
    }
    if (lane == 63) wsum2[wv] = x;
    __syncthreads();
    unsigned carry = 0;
    for (int w = 0; w < wv; ++w) carry += wsum2[w];
    unsigned base = carry + x - sum;
    if (2 * t <= NBIN)     tabL[2 * t] = base;
    if (2 * t + 1 <= NBIN) tabL[2 * t + 1] = base + loc0;
    __syncthreads();
    for (int i = t; i < NBIN; i += 256) cur[i] = tabL[i];
    __syncthreads();
    // pass 2: scatter into LDS buffer as u16
    for (unsigned i = st + t; i < en; i += 256) {
        unsigned r = rec[i];
        unsigned bin = (r & 0x1FFFFu) >> 8;
        unsigned p = atomicAdd(&cur[bin], 1u);
        buf[p] = (unsigned short)(((r >> 17) << 8) | (r & 255u));
    }
    __syncthreads();
    // coalesced flush + table write
    unsigned n = tabL[NBIN];
    unsigned* gout = (unsigned*)(rec16 + (size_t)b * CAP16);
    const unsigned* bin32 = (const unsigned*)buf;
    unsigned nw = (n + 1u) >> 1;
    for (unsigned i = t; i < nw; i += 256) gout[i] = bin32[i];
    for (int i = t; i <= NBIN; i += 256) tabG[b * (NBIN + 1) + i] = tabL[i];
}

// ---------------------------------------------------------------------------
// K5: one PageRank iteration — bin-parallel. Block = 256-node dst-bucket;
// each of 8 waves takes whole src-bins (bin index wave-uniform, NO bin walk).
// Within a bin, val reads hit a 1 KB window (<=16 lines) -> TA coalescing +
// L1 locality; records are u16, stream = 12.8 MB/iter.
// ---------------------------------------------------------------------------
__global__ __launch_bounds__(512)
void k_iterB(const unsigned short* __restrict__ rec16,
             const unsigned* __restrict__ tabG,
             const float* __restrict__ val, const float* __restrict__ s,
             float* __restrict__ pr, float* __restrict__ valn) {
    __shared__ float acc[DBS];
    __shared__ unsigned tab[NBIN + 1];
    int t = threadIdx.x;
    int b = blockIdx.x;
    if (t < DBS) acc[t] = 0.0f;
    if (t <= NBIN) tab[t] = tabG[b * (NBIN + 1) + t];
    __syncthreads();
    int wave = t >> 6, lane = t & 63;
    const unsigned short* rp = rec16 + (size_t)b * CAP16;
    for (int bin = wave; bin < NBIN; bin += 8) {
        unsigned st = tab[bin], en = tab[bin + 1];
        const float* vb = val + (bin << 8);
        for (unsigned i = st + lane; i < en; i += 64) {
            unsigned r = rp[i];
            atomicAdd(&acc[r >> 8], vb[r & 255u]);
        }
    }
    __syncthreads();
    if (t < DBS) {
        int v = b * DBS + t;
        if (v < N_NODES) {
            float pv = acc[t] + ALPHA / (float)N_NODES;
            pr[v] = pv;
            valn[v] = pv * s[v];
        }
    }
}

// ---------------------------------------------------------------------------
// K6: fused resizer + role solve + normalize. One 64-lane wave per output row.
// ---------------------------------------------------------------------------
__global__ __launch_bounds__(256)
void k_final(const float* __restrict__ emb, const float* __restrict__ rW,
             const float* __restrict__ rb, const int* __restrict__ batch,
             const float* __restrict__ deg, const float* __restrict__ pr,
             const float* __restrict__ M, float* __restrict__ out) {
    int wid  = (blockIdx.x * blockDim.x + threadIdx.x) >> 6;
    int lane = threadIdx.x & 63;
    if (wid >= N_NODES) return;

    const float* row = emb + (size_t)wid * DIM;
    float e0 = row[lane];
    float e1 = row[lane + 64];
    float2 w0 = ((const float2*)rW)[lane];
    float2 w1 = ((const float2*)rW)[lane + 64];
    float a0 = e0 * w0.x + e1 * w1.x;
    float a1 = e0 * w0.y + e1 * w1.y;
    #pragma unroll
    for (int off = 32; off; off >>= 1) {
        a0 += __shfl_xor(a0, off);
        a1 += __shfl_xor(a1, off);
    }

    int bn = batch[wid];
    float x0 = deg[bn];
    float x1 = pr[bn];
    float x2 = a0 + rb[0];
    float x3 = a1 + rb[1];

    float wr = 0.0f;
    if (lane < NROLES) {
        const float* m = M + lane * 4;
        wr = m[0] * x0 + m[1] * x1 + m[2] * x2 + m[3] * x3;
    }
    float sq = wr * wr;
    #pragma unroll
    for (int off = 4; off; off >>= 1) sq += __shfl_xor(sq, off);
    float inv = 1.0f / fmaxf(sqrtf(sq), 1e-12f);
    if (lane < NROLES) out[(size_t)wid * NROLES + lane] = wr * inv;
}

// ---------------------------------------------------------------------------
extern "C" void kernel_launch(void* const* d_in, const int* in_sizes, int n_in,
                              void* d_out, int out_size, void* d_ws, size_t ws_size,
                              hipStream_t stream) {
    const int*   edge  = (const int*)d_in[0];
    const int*   src   = edge;
    const int*   dst   = edge + N_EDGES;
    const int*   batch = (const int*)d_in[1];
    const float* emb   = (const float*)d_in[2];
    const float* rW    = (const float*)d_in[3];
    const float* rb    = (const float*)d_in[4];
    const float* H     = (const float*)d_in[5];
    float*       out   = (float*)d_out;

    // workspace carve-up (u32 words); rec16 overlays recs (recs fully
    // consumed by k_count_init before k_sort2 writes rec16).
    float*    deg    = (float*)d_ws;                 // 100352
    float*    s      = deg   + 100352;
    float*    pr     = s     + 100352;
    float*    valA   = pr    + 100352;
    float*    valB   = valA  + 100352;
    float*    M      = valB  + 100352;               // 32
    unsigned* counts = (unsigned*)(M + 32);          // 256*587
    unsigned* offs   = counts + NBLK_BIN * NBT;      // 256*587
    unsigned* btot   = offs   + NBLK_BIN * NBT;      // 1024
    unsigned* bases  = btot   + 1024;                // 1024 (dst@0, src@512)
    unsigned* rec    = bases  + 1024;                // 6.4M u32
    unsigned short* recs  = (unsigned short*)(rec + N_EDGES);  // 6.4M u16
    unsigned short* rec16 = recs;                    // 391*24576 u16 (overlay)
    unsigned* tabG   = (unsigned*)(rec16 + (size_t)NDB * CAP16); // 391*392

    k_prep_M<<<1, 1, 0, stream>>>(H, M);

    k_hist <<<NBLK_BIN, 256, 0, stream>>>(src, dst, counts);
    k_scanA<<<NBT,      256, 0, stream>>>(counts, offs, btot);
    k_scanB<<<2,        512, 0, stream>>>(btot, bases);
    k_place<<<NBLK_BIN, 256, 0, stream>>>(src, dst, offs, bases, rec, recs);
    k_count_init<<<NSB, 256, 0, stream>>>(recs, bases, deg, s, valA);
    k_sort2<<<NDB,      256, 0, stream>>>(rec, bases, rec16, tabG);

    float* vcur = valA;
    float* vnxt = valB;
    for (int it = 0; it < PR_ITERS; ++it) {
        k_iterB<<<NDB, 512, 0, stream>>>(rec16, tabG, vcur, s, pr, vnxt);
        float* t = vcur; vcur = vnxt; vnxt = t;
    }

    const int FG = (N_NODES + 3) / 4;
    k_final<<<FG, 256, 0, stream>>>(emb, rW, rb, batch, deg, pr, M, out);
}

// Round 11
// 518.437 us; speedup vs baseline: 1.2129x; 1.2129x over previous
//
#include <hip/hip_runtime.h>
#include <math.h>

#define N_NODES 100000
#define N_EDGES 6400000
#define DIM     128
#define NROLES  8
#define ALPHA   0.15f
#define PR_ITERS 10

#define BUCKET_SHIFT 9
#define BUCKET_SIZE  512
#define NBUCKET      196          // ceil(100000/512)
#define NB2          392          // dst buckets [0,196) + src buckets [196,392)
#define NBLK_BIN     512
#define CHUNK        12500        // E / NBLK_BIN exactly
#define SEG          8            // segments per bucket in the iteration

// ---------------------------------------------------------------------------
// K0: tiny fp64 solve on device: M = A^T (A A^T)^{-1}, A = H^T (4 x R).
// ---------------------------------------------------------------------------
__global__ void k_prep_M(const float* __restrict__ H, float* __restrict__ Mout) {
    if (threadIdx.x != 0 || blockIdx.x != 0) return;
    double G[4][4];
    for (int i = 0; i < 4; ++i)
        for (int j = 0; j < 4; ++j) {
            double s = 0.0;
            for (int r = 0; r < NROLES; ++r)
                s += (double)H[r * 4 + i] * (double)H[r * 4 + j];
            G[i][j] = s;
        }
    double aug[4][8];
    for (int i = 0; i < 4; ++i)
        for (int j = 0; j < 4; ++j) {
            aug[i][j] = G[i][j];
            aug[i][j + 4] = (i == j) ? 1.0 : 0.0;
        }
    for (int c = 0; c < 4; ++c) {
        int p = c; double best = fabs(aug[c][c]);
        for (int r = c + 1; r < 4; ++r) {
            double v = fabs(aug[r][c]);
            if (v > best) { best = v; p = r; }
        }
        if (p != c)
            for (int j = 0; j < 8; ++j) {
                double t = aug[c][j]; aug[c][j] = aug[p][j]; aug[p][j] = t;
            }
        double piv = aug[c][c];
        for (int j = 0; j < 8; ++j) aug[c][j] /= piv;
        for (int r = 0; r < 4; ++r) {
            if (r == c) continue;
            double f = aug[r][c];
            for (int j = 0; j < 8; ++j) aug[r][j] -= f * aug[c][j];
        }
    }
    for (int r = 0; r < NROLES; ++r)
        for (int k = 0; k < 4; ++k) {
            double s = 0.0;
            for (int j = 0; j < 4; ++j)
                s += (double)H[r * 4 + j] * aug[j][k + 4];
            Mout[r * 4 + k] = (float)s;
        }
}

// ---------------------------------------------------------------------------
// K1: per-block LDS histograms over BOTH dst-buckets and src-buckets.
// 512 blocks x 12500 edges.
// ---------------------------------------------------------------------------
__global__ __launch_bounds__(256)
void k_hist(const int* __restrict__ src, const int* __restrict__ dst,
            unsigned* __restrict__ counts) {
    __shared__ unsigned h[NB2];
    for (int i = threadIdx.x; i < NB2; i += 256) h[i] = 0;
    __syncthreads();
    int beg = blockIdx.x * CHUNK;
    int t = threadIdx.x;
    int mainEnd = beg + 12288;
    for (int e = beg + t * 4; e < mainEnd; e += 1024) {
        int4 s4 = *(const int4*)(src + e);
        int4 d4 = *(const int4*)(dst + e);
        atomicAdd(&h[((unsigned)d4.x) >> BUCKET_SHIFT], 1u);
        atomicAdd(&h[((unsigned)d4.y) >> BUCKET_SHIFT], 1u);
        atomicAdd(&h[((unsigned)d4.z) >> BUCKET_SHIFT], 1u);
        atomicAdd(&h[((unsigned)d4.w) >> BUCKET_SHIFT], 1u);
        atomicAdd(&h[NBUCKET + (((unsigned)s4.x) >> BUCKET_SHIFT)], 1u);
        atomicAdd(&h[NBUCKET + (((unsigned)s4.y) >> BUCKET_SHIFT)], 1u);
        atomicAdd(&h[NBUCKET + (((unsigned)s4.z) >> BUCKET_SHIFT)], 1u);
        atomicAdd(&h[NBUCKET + (((unsigned)s4.w) >> BUCKET_SHIFT)], 1u);
    }
    for (int e = mainEnd + t; e < beg + CHUNK; e += 256) {
        atomicAdd(&h[((unsigned)dst[e]) >> BUCKET_SHIFT], 1u);
        atomicAdd(&h[NBUCKET + (((unsigned)src[e]) >> BUCKET_SHIFT)], 1u);
    }
    __syncthreads();
    for (int i = threadIdx.x; i < NB2; i += 256)
        counts[blockIdx.x * NB2 + i] = h[i];
}

// ---------------------------------------------------------------------------
// K2a: per-bucket exclusive scan over the 512 per-block counts.
// ---------------------------------------------------------------------------
__global__ __launch_bounds__(512)
void k_scanA(const unsigned* __restrict__ counts, unsigned* __restrict__ offs,
             unsigned* __restrict__ btot) {
    int bucket = blockIdx.x, t = threadIdx.x, lane = t & 63, wv = t >> 6;
    unsigned v = counts[t * NB2 + bucket], x = v;
    #pragma unroll
    for (int o = 1; o < 64; o <<= 1) {
        unsigned y = __shfl_up(x, o);
        if (lane >= o) x += y;
    }
    __shared__ unsigned wsum[8];
    if (lane == 63) wsum[wv] = x;
    __syncthreads();
    unsigned carry = 0;
    for (int w = 0; w < wv; ++w) carry += wsum[w];
    x += carry;
    offs[t * NB2 + bucket] = x - v;       // exclusive
    if (t == 511) btot[bucket] = x;       // inclusive total
}

// ---------------------------------------------------------------------------
// K2b: exclusive scan of 196 bucket totals for each half (dst, src).
// ---------------------------------------------------------------------------
__global__ __launch_bounds__(256)
void k_scanB(const unsigned* __restrict__ btot, unsigned* __restrict__ bases) {
    int half = blockIdx.x;
    int t = threadIdx.x, lane = t & 63, wv = t >> 6;
    unsigned v = (t < NBUCKET) ? btot[half * NBUCKET + t] : 0u, x = v;
    #pragma unroll
    for (int o = 1; o < 64; o <<= 1) {
        unsigned y = __shfl_up(x, o);
        if (lane >= o) x += y;
    }
    __shared__ unsigned wsum[4];
    if (lane == 63) wsum[wv] = x;
    __syncthreads();
    unsigned carry = 0;
    for (int w = 0; w < wv; ++w) carry += wsum[w];
    x += carry;
    if (t <= NBUCKET) bases[half * 256 + t] = x - v;   // exclusive
}

// ---------------------------------------------------------------------------
// K3: placement with LDS-local counting sort + line-granular flush.
// Per block (12500 edges): local scan of this block's bucket counts (from
// k_hist), scatter records into LDS, then flush each bucket's run as ONE
// contiguous coalesced store. Every global line is written once.
// Pass A: rec (u32, dst-bucketed). Pass B: recs (u16, src-bucketed).
// ---------------------------------------------------------------------------
__global__ __launch_bounds__(512)
void k_place(const int* __restrict__ src, const int* __restrict__ dst,
             const unsigned* __restrict__ counts, const unsigned* __restrict__ offs,
             const unsigned* __restrict__ bases,
             unsigned* __restrict__ rec, unsigned short* __restrict__ recs) {
    __shared__ unsigned buf[CHUNK];           // 50 KB; u16 overlay in pass B
    __shared__ unsigned loc[NBUCKET + 1];
    __shared__ unsigned cur[NBUCKET];
    __shared__ unsigned wsum[8];
    int t = threadIdx.x, lane = t & 63, wv = t >> 6;
    int blk = blockIdx.x;
    int beg = blk * CHUNK;
    int mainEnd = beg + 12288;

    // ===== pass A: dst buckets -> rec (u32) =====
    {
        unsigned c = (t < NBUCKET) ? counts[blk * NB2 + t] : 0u;
        unsigned x = c;
        #pragma unroll
        for (int o = 1; o < 64; o <<= 1) {
            unsigned y = __shfl_up(x, o);
            if (lane >= o) x += y;
        }
        if (lane == 63) wsum[wv] = x;
        __syncthreads();
        unsigned carry = 0;
        for (int w = 0; w < wv; ++w) carry += wsum[w];
        x += carry;
        if (t < NBUCKET) { loc[t] = x - c; cur[t] = x - c; }
        if (t == NBUCKET - 1) loc[NBUCKET] = x;
    }
    __syncthreads();
    for (int e = beg + t * 4; e < mainEnd; e += 2048) {
        int4 s4 = *(const int4*)(src + e);
        int4 d4 = *(const int4*)(dst + e);
        #pragma unroll
        for (int k = 0; k < 4; ++k) {
            unsigned s = (unsigned)((&s4.x)[k]);
            unsigned d = (unsigned)((&d4.x)[k]);
            unsigned p = atomicAdd(&cur[d >> BUCKET_SHIFT], 1u);
            buf[p] = ((d & (BUCKET_SIZE - 1)) << 17) | s;
        }
    }
    for (int e = mainEnd + t; e < beg + CHUNK; e += 512) {
        unsigned s = (unsigned)src[e];
        unsigned d = (unsigned)dst[e];
        unsigned p = atomicAdd(&cur[d >> BUCKET_SHIFT], 1u);
        buf[p] = ((d & (BUCKET_SIZE - 1)) << 17) | s;
    }
    __syncthreads();
    for (int i = wv; i < NBUCKET; i += 8) {
        unsigned lo = loc[i], n = loc[i + 1] - lo;
        unsigned gbase = bases[i] + offs[blk * NB2 + i];
        for (unsigned j = lane; j < n; j += 64)
            rec[gbase + j] = buf[lo + j];
    }
    __syncthreads();

    // ===== pass B: src buckets -> recs (u16) =====
    {
        unsigned c = (t < NBUCKET) ? counts[blk * NB2 + NBUCKET + t] : 0u;
        unsigned x = c;
        #pragma unroll
        for (int o = 1; o < 64; o <<= 1) {
            unsigned y = __shfl_up(x, o);
            if (lane >= o) x += y;
        }
        if (lane == 63) wsum[wv] = x;
        __syncthreads();
        unsigned carry = 0;
        for (int w = 0; w < wv; ++w) carry += wsum[w];
        x += carry;
        if (t < NBUCKET) { loc[t] = x - c; cur[t] = x - c; }
        if (t == NBUCKET - 1) loc[NBUCKET] = x;
    }
    __syncthreads();
    unsigned short* b16 = (unsigned short*)buf;
    for (int e = beg + t * 4; e < mainEnd; e += 2048) {
        int4 s4 = *(const int4*)(src + e);
        #pragma unroll
        for (int k = 0; k < 4; ++k) {
            unsigned s = (unsigned)((&s4.x)[k]);
            unsigned p = atomicAdd(&cur[s >> BUCKET_SHIFT], 1u);
            b16[p] = (unsigned short)(s & (BUCKET_SIZE - 1));
        }
    }
    for (int e = mainEnd + t; e < beg + CHUNK; e += 512) {
        unsigned s = (unsigned)src[e];
        unsigned p = atomicAdd(&cur[s >> BUCKET_SHIFT], 1u);
        b16[p] = (unsigned short)(s & (BUCKET_SIZE - 1));
    }
    __syncthreads();
    for (int i = wv; i < NBUCKET; i += 8) {
        unsigned lo = loc[i], n = loc[i + 1] - lo;
        unsigned gbase = bases[256 + i] + offs[blk * NB2 + NBUCKET + i];
        for (unsigned j = lane; j < n; j += 64)
            recs[gbase + j] = b16[lo + j];
    }
}

// ---------------------------------------------------------------------------
// K4: per-src-bucket degree count (LDS u32) + fused init of s and val0.
// ---------------------------------------------------------------------------
__global__ __launch_bounds__(256)
void k_count_init(const unsigned short* __restrict__ recs,
                  const unsigned* __restrict__ bases,
                  float* __restrict__ deg, float* __restrict__ s,
                  float* __restrict__ val0) {
    __shared__ unsigned cnt[BUCKET_SIZE];
    int t = threadIdx.x;
    cnt[t] = 0; cnt[t + 256] = 0;
    __syncthreads();
    int b = blockIdx.x;
    unsigned st = bases[256 + b], en = bases[256 + b + 1];
    unsigned a = (st + 7u) & ~7u;
    if (a > en) a = en;
    for (unsigned i = st + t; i < a; i += 256)
        atomicAdd(&cnt[recs[i]], 1u);
    unsigned mainN = (en - a) & ~2047u;
    const uint4* rp = (const uint4*)(recs + a);
    for (unsigned i = t; i * 8u < mainN; i += 256) {
        uint4 r = rp[i];
        atomicAdd(&cnt[r.x & 0xFFFFu], 1u); atomicAdd(&cnt[r.x >> 16], 1u);
        atomicAdd(&cnt[r.y & 0xFFFFu], 1u); atomicAdd(&cnt[r.y >> 16], 1u);
        atomicAdd(&cnt[r.z & 0xFFFFu], 1u); atomicAdd(&cnt[r.z >> 16], 1u);
        atomicAdd(&cnt[r.w & 0xFFFFu], 1u); atomicAdd(&cnt[r.w >> 16], 1u);
    }
    for (unsigned i = a + mainN + t; i < en; i += 256)
        atomicAdd(&cnt[recs[i]], 1u);
    __syncthreads();
    #pragma unroll
    for (int k = 0; k < 2; ++k) {
        int v = b * BUCKET_SIZE + t + k * 256;
        if (v < N_NODES) {
            float d = (float)cnt[t + k * 256];
            float sv = (1.0f - ALPHA) / fmaxf(d, 1.0f);
            deg[v] = d;
            s[v] = sv;
            val0[v] = sv * (1.0f / (float)N_NODES);
        }
    }
}

// ---------------------------------------------------------------------------
// K5: segmented PageRank accumulate: block = (bucket, segment).
// ---------------------------------------------------------------------------
__global__ __launch_bounds__(256)
void k_iter2(const unsigned* __restrict__ rec, const unsigned* __restrict__ bases,
             const float* __restrict__ val, float* __restrict__ partial) {
    __shared__ float acc[BUCKET_SIZE];
    int t = threadIdx.x;
    acc[t] = 0.0f;
    acc[t + 256] = 0.0f;
    __syncthreads();
    int b   = blockIdx.x >> 3;       // SEG = 8
    int seg = blockIdx.x & 7;
    unsigned st = bases[b], en = bases[b + 1], n = en - st;
    unsigned s0 = st + (unsigned)(((unsigned long long)n * (unsigned)seg) >> 3);
    unsigned s1 = st + (unsigned)(((unsigned long long)n * (unsigned)(seg + 1)) >> 3);
    unsigned a0 = (s0 + 3u) & ~3u;
    if (a0 > s1) a0 = s1;
    unsigned nq = (s1 - a0) >> 2;
    unsigned nh = nq >> 1;
    const uint4* rp = (const uint4*)(rec + a0);
    unsigned tail0 = a0 + 8u * nh;
    for (unsigned i = s0 + t; i < a0; i += 256) {
        unsigned r = rec[i];
        atomicAdd(&acc[r >> 17], val[r & 0x1FFFFu]);
    }
    for (unsigned i = t; i < nh; i += 256) {
        uint4 ra = rp[i];
        uint4 rb2 = rp[i + nh];
        float v0 = val[ra.x & 0x1FFFFu];
        float v1 = val[ra.y & 0x1FFFFu];
        float v2 = val[ra.z & 0x1FFFFu];
        float v3 = val[ra.w & 0x1FFFFu];
        float v4 = val[rb2.x & 0x1FFFFu];
        float v5 = val[rb2.y & 0x1FFFFu];
        float v6 = val[rb2.z & 0x1FFFFu];
        float v7 = val[rb2.w & 0x1FFFFu];
        atomicAdd(&acc[ra.x >> 17], v0);
        atomicAdd(&acc[ra.y >> 17], v1);
        atomicAdd(&acc[ra.z >> 17], v2);
        atomicAdd(&acc[ra.w >> 17], v3);
        atomicAdd(&acc[rb2.x >> 17], v4);
        atomicAdd(&acc[rb2.y >> 17], v5);
        atomicAdd(&acc[rb2.z >> 17], v6);
        atomicAdd(&acc[rb2.w >> 17], v7);
    }
    for (unsigned i = tail0 + t; i < s1; i += 256) {
        unsigned r = rec[i];
        atomicAdd(&acc[r >> 17], val[r & 0x1FFFFu]);
    }
    __syncthreads();
    float* p = partial + ((unsigned)blockIdx.x << 9);
    p[t] = acc[t];
    p[t + 256] = acc[t + 256];
}

// ---------------------------------------------------------------------------
// K5b: reduce 8 partials per node -> pr, valn.
// ---------------------------------------------------------------------------
__global__ __launch_bounds__(256)
void k_reduce(const float* __restrict__ partial, const float* __restrict__ s,
              float* __restrict__ pr, float* __restrict__ valn) {
    int v = blockIdx.x * 256 + threadIdx.x;
    if (v >= N_NODES) return;
    int b = v >> BUCKET_SHIFT, local = v & (BUCKET_SIZE - 1);
    const float* p = partial + ((unsigned)(b * SEG) << 9) + local;
    float sum = 0.0f;
    #pragma unroll
    for (int k = 0; k < SEG; ++k) sum += p[k << 9];
    float pv = sum + ALPHA / (float)N_NODES;
    pr[v] = pv;
    valn[v] = pv * s[v];
}

// ---------------------------------------------------------------------------
// K6: fused resizer + role solve + normalize. One 64-lane wave per output row.
// ---------------------------------------------------------------------------
__global__ __launch_bounds__(256)
void k_final(const float* __restrict__ emb, const float* __restrict__ rW,
             const float* __restrict__ rb, const int* __restrict__ batch,
             const float* __restrict__ deg, const float* __restrict__ pr,
             const float* __restrict__ M, float* __restrict__ out) {
    int wid  = (blockIdx.x * blockDim.x + threadIdx.x) >> 6;
    int lane = threadIdx.x & 63;
    if (wid >= N_NODES) return;

    const float* row = emb + (size_t)wid * DIM;
    float e0 = row[lane];
    float e1 = row[lane + 64];
    float2 w0 = ((const float2*)rW)[lane];
    float2 w1 = ((const float2*)rW)[lane + 64];
    float a0 = e0 * w0.x + e1 * w1.x;
    float a1 = e0 * w0.y + e1 * w1.y;
    #pragma unroll
    for (int off = 32; off; off >>= 1) {
        a0 += __shfl_xor(a0, off);
        a1 += __shfl_xor(a1, off);
    }

    int bn = batch[wid];
    float x0 = deg[bn];
    float x1 = pr[bn];
    float x2 = a0 + rb[0];
    float x3 = a1 + rb[1];

    float wr = 0.0f;
    if (lane < NROLES) {
        const float* m = M + lane * 4;
        wr = m[0] * x0 + m[1] * x1 + m[2] * x2 + m[3] * x3;
    }
    float sq = wr * wr;
    #pragma unroll
    for (int off = 4; off; off >>= 1) sq += __shfl_xor(sq, off);
    float inv = 1.0f / fmaxf(sqrtf(sq), 1e-12f);
    if (lane < NROLES) out[(size_t)wid * NROLES + lane] = wr * inv;
}

// ---------------------------------------------------------------------------
extern "C" void kernel_launch(void* const* d_in, const int* in_sizes, int n_in,
                              void* d_out, int out_size, void* d_ws, size_t ws_size,
                              hipStream_t stream) {
    const int*   edge  = (const int*)d_in[0];
    const int*   src   = edge;
    const int*   dst   = edge + N_EDGES;
    const int*   batch = (const int*)d_in[1];
    const float* emb   = (const float*)d_in[2];
    const float* rW    = (const float*)d_in[3];
    const float* rb    = (const float*)d_in[4];
    const float* H     = (const float*)d_in[5];
    float*       out   = (float*)d_out;

    // workspace carve-up (u32 words)
    float*    deg    = (float*)d_ws;                 // 100352
    float*    s      = deg   + 100352;
    float*    pr     = s     + 100352;
    float*    valA   = pr    + 100352;
    float*    valB   = valA  + 100352;
    float*    M      = valB  + 100352;               // 32
    unsigned* counts = (unsigned*)(M + 32);          // 512*392
    unsigned* offs   = counts + NBLK_BIN * NB2;      // 512*392
    unsigned* btot   = offs   + NBLK_BIN * NB2;      // 512
    unsigned* bases  = btot   + 512;                 // 512 (dst@0, src@256)
    unsigned* rec    = bases  + 512;                 // 6.4M u32
    unsigned short* recs = (unsigned short*)(rec + N_EDGES);  // 6.4M u16
    float*    partial = (float*)(recs + N_EDGES);    // 1568*512 f32

    k_prep_M<<<1, 1, 0, stream>>>(H, M);

    k_hist <<<NBLK_BIN, 256, 0, stream>>>(src, dst, counts);
    k_scanA<<<NB2,      512, 0, stream>>>(counts, offs, btot);
    k_scanB<<<2,        256, 0, stream>>>(btot, bases);
    k_place<<<NBLK_BIN, 512, 0, stream>>>(src, dst, counts, offs, bases, rec, recs);
    k_count_init<<<NBUCKET, 256, 0, stream>>>(recs, bases, deg, s, valA);

    float* vcur = valA;
    float* vnxt = valB;
    for (int it = 0; it < PR_ITERS; ++it) {
        k_iter2 <<<NBUCKET * SEG, 256, 0, stream>>>(rec, bases, vcur, partial);
        k_reduce<<<(N_NODES + 255) / 256, 256, 0, stream>>>(partial, s, pr, vnxt);
        float* t = vcur; vcur = vnxt; vnxt = t;
    }

    const int FG = (N_NODES + 3) / 4;
    k_final<<<FG, 256, 0, stream>>>(emb, rW, rb, batch, deg, pr, M, out);
}